// Round 1
// baseline (2233.339 us; speedup 1.0000x reference)
//
#include <hip/hip_runtime.h>
#include <hip/hip_bf16.h>

// Problem constants (from reference): B=2, T=2048, D=1024, H=16, DK=64
constexpr int Bc = 2;
constexpr int Tc = 2048;
constexpr int Dc = 1024;
constexpr int Hc = 16;
constexpr int DKc = 64;
constexpr int Mc = Bc * Tc;  // 4096 rows for projection GEMMs

// ---------------------------------------------------------------------------
// GEMM: C[M,N] = A[M,K] @ W[K,N] + bias[N]   (fp32, 64x64 tile, 4x4 microtile)
// M=4096, N=1024, K=1024 — all multiples of tile sizes, no bounds checks.
// ---------------------------------------------------------------------------
__global__ __launch_bounds__(256) void gemm_bias(const float* __restrict__ A,
                                                 const float* __restrict__ W,
                                                 const float* __restrict__ bias,
                                                 float* __restrict__ C,
                                                 int M, int N, int K) {
    constexpr int TM = 64, TN = 64, TK = 16;
    __shared__ float As[TK][TM + 2];  // [k][m], +2 pad: 2-way max on store/load
    __shared__ float Ws[TK][TN + 1];  // [k][n]

    const int tid = threadIdx.x;
    const int bm = blockIdx.y * TM;
    const int bn = blockIdx.x * TN;
    const int tx = tid & 15;   // n direction (4 cols each)
    const int ty = tid >> 4;   // m direction (4 rows each)

    float acc[4][4] = {};

    for (int k0 = 0; k0 < K; k0 += TK) {
        // Load A tile (64 rows x 16 k): thread -> row tid>>2, 4 consecutive k
        {
            const int m = tid >> 2;
            const int kk = (tid & 3) * 4;
            const float4 v = *(const float4*)(A + (size_t)(bm + m) * K + k0 + kk);
            As[kk + 0][m] = v.x;
            As[kk + 1][m] = v.y;
            As[kk + 2][m] = v.z;
            As[kk + 3][m] = v.w;
        }
        // Load W tile (16 k x 64 n): thread -> k = tid>>4, 4 consecutive n
        {
            const int k = tid >> 4;
            const int n0 = (tid & 15) * 4;
            const float4 v = *(const float4*)(W + (size_t)(k0 + k) * N + bn + n0);
            Ws[k][n0 + 0] = v.x;
            Ws[k][n0 + 1] = v.y;
            Ws[k][n0 + 2] = v.z;
            Ws[k][n0 + 3] = v.w;
        }
        __syncthreads();
#pragma unroll
        for (int k = 0; k < TK; ++k) {
            float a[4], w[4];
#pragma unroll
            for (int i = 0; i < 4; ++i) a[i] = As[k][ty * 4 + i];
#pragma unroll
            for (int j = 0; j < 4; ++j) w[j] = Ws[k][tx * 4 + j];
#pragma unroll
            for (int i = 0; i < 4; ++i)
#pragma unroll
                for (int j = 0; j < 4; ++j) acc[i][j] += a[i] * w[j];
        }
        __syncthreads();
    }

#pragma unroll
    for (int i = 0; i < 4; ++i) {
        const int m = bm + ty * 4 + i;
#pragma unroll
        for (int j = 0; j < 4; ++j) {
            const int n = bn + tx * 4 + j;
            C[(size_t)m * N + n] = acc[i][j] + bias[n];
        }
    }
}

// ---------------------------------------------------------------------------
// Flash-style causal attention, fp32.
// Grid: (T/BQ, B*H). Block: 256 threads.
// Q/K/V/ctx layout: (B, T, D) with head h occupying cols [h*DK, (h+1)*DK).
// Each block: 32 query rows, loops K/V tiles of 64 up to the causal boundary.
// Online softmax: m,l per row in LDS; O accumulator (8 floats) in registers.
// Thread map for S and PV: qi = tid>>3 (0..31), c0 = (tid&7)*8 (cols 8-wide).
// ---------------------------------------------------------------------------
__global__ __launch_bounds__(256) void attn_causal(const float* __restrict__ Qg,
                                                   const float* __restrict__ Kg,
                                                   const float* __restrict__ Vg,
                                                   float* __restrict__ Og) {
    constexpr int BQ = 32, BK = 64;
    constexpr float SCALE = 0.125f;  // 1/sqrt(64)
    constexpr float NEG = -1e30f;

    __shared__ float Qs[BQ][DKc + 1];  // [q][d]
    __shared__ float Kt[DKc][BK + 1];  // [d][k]  (transposed)
    __shared__ float Vs[BK][DKc + 1];  // [k][d]
    __shared__ float Sm[BQ][BK + 1];   // scores -> probabilities
    __shared__ float m_s[BQ], l_s[BQ], a_s[BQ];

    const int tid = threadIdx.x;
    const int bh = blockIdx.y;
    const int b = bh >> 4;
    const int h = bh & (Hc - 1);
    const int q0 = blockIdx.x * BQ;
    const size_t base = ((size_t)b * Tc) * Dc + (size_t)h * DKc;

    const int qi = tid >> 3;        // 0..31
    const int c0 = (tid & 7) * 8;   // 0,8,...,56

    // Load Q tile: each thread 8 consecutive floats of one row
    {
        const float4* src = (const float4*)(Qg + base + (size_t)(q0 + qi) * Dc + c0);
        const float4 v0 = src[0], v1 = src[1];
        Qs[qi][c0 + 0] = v0.x; Qs[qi][c0 + 1] = v0.y;
        Qs[qi][c0 + 2] = v0.z; Qs[qi][c0 + 3] = v0.w;
        Qs[qi][c0 + 4] = v1.x; Qs[qi][c0 + 5] = v1.y;
        Qs[qi][c0 + 6] = v1.z; Qs[qi][c0 + 7] = v1.w;
    }
    if (tid < BQ) { m_s[tid] = NEG; l_s[tid] = 0.0f; }
    float o[8] = {0.f, 0.f, 0.f, 0.f, 0.f, 0.f, 0.f, 0.f};
    __syncthreads();

    const int kend = q0 + BQ;  // exclusive causal bound for this q tile
    for (int k0 = 0; k0 < kend; k0 += BK) {
        // Load K (transposed) and V tiles: thread -> row kr=tid>>2, 16 floats
        {
            const int kr = tid >> 2;
            const int dd = (tid & 3) * 16;
            const float4* kp = (const float4*)(Kg + base + (size_t)(k0 + kr) * Dc + dd);
            const float4* vp = (const float4*)(Vg + base + (size_t)(k0 + kr) * Dc + dd);
#pragma unroll
            for (int u = 0; u < 4; ++u) {
                const float4 kv = kp[u];
                const float4 vv = vp[u];
                const int d = dd + u * 4;
                Kt[d + 0][kr] = kv.x; Kt[d + 1][kr] = kv.y;
                Kt[d + 2][kr] = kv.z; Kt[d + 3][kr] = kv.w;
                Vs[kr][d + 0] = vv.x; Vs[kr][d + 1] = vv.y;
                Vs[kr][d + 2] = vv.z; Vs[kr][d + 3] = vv.w;
            }
        }
        __syncthreads();

        // S = Q @ K^T for this tile (each thread: 1 q row x 8 k cols)
        {
            float s[8] = {0.f, 0.f, 0.f, 0.f, 0.f, 0.f, 0.f, 0.f};
#pragma unroll 8
            for (int d = 0; d < DKc; ++d) {
                const float qd = Qs[qi][d];
#pragma unroll
                for (int j = 0; j < 8; ++j) s[j] += qd * Kt[d][c0 + j];
            }
            const int q = q0 + qi;
#pragma unroll
            for (int j = 0; j < 8; ++j) {
                const int kk = k0 + c0 + j;
                Sm[qi][c0 + j] = (kk <= q) ? s[j] * SCALE : NEG;
            }
        }
        __syncthreads();

        // Online softmax row update (one thread per q row)
        if (tid < BQ) {
            float m = m_s[tid];
            float rmax = NEG;
            for (int k = 0; k < BK; ++k) rmax = fmaxf(rmax, Sm[tid][k]);
            const float nm = fmaxf(m, rmax);
            const float alpha = __expf(m - nm);  // m==NEG -> 0
            float sum = 0.f;
            for (int k = 0; k < BK; ++k) {
                const float p = __expf(Sm[tid][k] - nm);
                Sm[tid][k] = p;
                sum += p;
            }
            m_s[tid] = nm;
            l_s[tid] = l_s[tid] * alpha + sum;
            a_s[tid] = alpha;
        }
        __syncthreads();

        // Rescale O and accumulate P @ V (each thread: 1 q row x 8 d cols)
        {
            const float alpha = a_s[qi];
#pragma unroll
            for (int j = 0; j < 8; ++j) o[j] *= alpha;
#pragma unroll 8
            for (int k = 0; k < BK; ++k) {
                const float p = Sm[qi][k];
#pragma unroll
                for (int j = 0; j < 8; ++j) o[j] += p * Vs[k][c0 + j];
            }
        }
        __syncthreads();
    }

    const float inv_l = 1.0f / l_s[qi];
    float* op = Og + base + (size_t)(q0 + qi) * Dc + c0;
    float4 r0, r1;
    r0.x = o[0] * inv_l; r0.y = o[1] * inv_l;
    r0.z = o[2] * inv_l; r0.w = o[3] * inv_l;
    r1.x = o[4] * inv_l; r1.y = o[5] * inv_l;
    r1.z = o[6] * inv_l; r1.w = o[7] * inv_l;
    ((float4*)op)[0] = r0;
    ((float4*)op)[1] = r1;
}

// ---------------------------------------------------------------------------
// kernel_launch
// Workspace: Q | K | V | ctx, each M*D fp32 = 16 MB -> 64 MB total.
// ---------------------------------------------------------------------------
extern "C" void kernel_launch(void* const* d_in, const int* in_sizes, int n_in,
                              void* d_out, int out_size, void* d_ws, size_t ws_size,
                              hipStream_t stream) {
    const float* x  = (const float*)d_in[0];
    const float* Wq = (const float*)d_in[1];
    const float* bq = (const float*)d_in[2];
    const float* Wk = (const float*)d_in[3];
    const float* bk = (const float*)d_in[4];
    const float* Wv = (const float*)d_in[5];
    const float* bv = (const float*)d_in[6];
    const float* Wo = (const float*)d_in[7];
    const float* bo = (const float*)d_in[8];
    float* out = (float*)d_out;

    float* Q   = (float*)d_ws;
    float* K   = Q + (size_t)Mc * Dc;
    float* V   = K + (size_t)Mc * Dc;
    float* ctx = V + (size_t)Mc * Dc;

    const dim3 gblk(256);
    const dim3 ggrid(Dc / 64, Mc / 64);  // N tiles x M tiles

    gemm_bias<<<ggrid, gblk, 0, stream>>>(x, Wq, bq, Q, Mc, Dc, Dc);
    gemm_bias<<<ggrid, gblk, 0, stream>>>(x, Wk, bk, K, Mc, Dc, Dc);
    gemm_bias<<<ggrid, gblk, 0, stream>>>(x, Wv, bv, V, Mc, Dc, Dc);

    const dim3 agrid(Tc / 32, Bc * Hc);
    attn_causal<<<agrid, gblk, 0, stream>>>(Q, K, V, ctx);

    gemm_bias<<<ggrid, gblk, 0, stream>>>(ctx, Wo, bo, out, Mc, Dc, Dc);
}

// Round 2
// 737.413 us; speedup vs baseline: 3.0286x; 3.0286x over previous
//
#include <hip/hip_runtime.h>
#include <hip/hip_bf16.h>

// Problem constants: B=2, T=2048, D=1024, H=16, DK=64
constexpr int Bc = 2;
constexpr int Tc = 2048;
constexpr int Mc = Bc * Tc;  // 4096

typedef __attribute__((ext_vector_type(8))) __bf16 bf16x8;
typedef __attribute__((ext_vector_type(4))) __bf16 bf16x4;
typedef __attribute__((ext_vector_type(4))) float floatx4;

__device__ __forceinline__ void gl_lds16(const void* g, void* l) {
    __builtin_amdgcn_global_load_lds(
        (const __attribute__((address_space(1))) void*)g,
        (__attribute__((address_space(3))) void*)l, 16, 0, 0);
}

// ---------------------------------------------------------------------------
// fp32 -> bf16 elementwise convert (x and nothing else; ctx converts in-kernel)
// ---------------------------------------------------------------------------
__global__ __launch_bounds__(256) void cvt_bf16(const float* __restrict__ in,
                                                __bf16* __restrict__ out, int n) {
    const int i = (blockIdx.x * 256 + threadIdx.x) * 4;
    if (i < n) {
        const float4 v = *(const float4*)(in + i);
        bf16x4 r;
        r[0] = (__bf16)v.x; r[1] = (__bf16)v.y;
        r[2] = (__bf16)v.z; r[3] = (__bf16)v.w;
        *(bf16x4*)(out + i) = r;
    }
}

// ---------------------------------------------------------------------------
// Weight transpose+convert: W fp32 [1024][1024] (in,out) -> Wt bf16 [1024][1024]
// (out,in) so the GEMM can consume B^T with k-contiguous rows.
// 64x64 tiles via LDS, coalesced read and write.
// ---------------------------------------------------------------------------
__global__ __launch_bounds__(256) void wtrans_bf16(const float* __restrict__ W,
                                                   __bf16* __restrict__ Wt) {
    __shared__ float t[64][65];
    const int k0 = blockIdx.y * 64, n0 = blockIdx.x * 64;
    const int c = threadIdx.x & 63, r0 = threadIdx.x >> 6;
#pragma unroll
    for (int i = 0; i < 16; ++i)
        t[r0 + i * 4][c] = W[(size_t)(k0 + r0 + i * 4) * 1024 + n0 + c];
    __syncthreads();
#pragma unroll
    for (int i = 0; i < 16; ++i) {
        const int r = r0 + i * 4;
        Wt[(size_t)(n0 + r) * 1024 + k0 + c] = (__bf16)t[c][r];
    }
}

// ---------------------------------------------------------------------------
// bf16 MFMA GEMM, m97 structure: C[M,N] = A[M,K] @ Bt[N,K]^T + bias
// 128x128 tile, BK=32, 256 threads = 4 waves (2x2), each wave 64x64 via
// 4x4 grid of mfma_f32_16x16x32_bf16. global_load_lds width-16 staging.
// A-frag: A[m=lane&15][k=quad*8+j]; B-frag mirrored; C/D: col=lane&15,
// row=quad*4+reg (m89/m91-verified layouts).
// Bias select by output column segment (QKV concat: bq|bk|bv).
// ---------------------------------------------------------------------------
template <bool BF16_OUT>
__global__ __launch_bounds__(256) void gemm_bt(const __bf16* __restrict__ A,
                                               const __bf16* __restrict__ Bt,
                                               const float* __restrict__ b0,
                                               const float* __restrict__ b1,
                                               const float* __restrict__ b2,
                                               void* __restrict__ Cv,
                                               int M, int N, int K) {
    __shared__ __bf16 As[128 * 32];
    __shared__ __bf16 Bs[128 * 32];
    const int tid = threadIdx.x, lane = tid & 63, wave = tid >> 6;
    const int wm = wave & 1, wn = wave >> 1;
    const int bm = blockIdx.y * 128, bn = blockIdx.x * 128;
    const __bf16* Ab = A + (size_t)bm * K;
    const __bf16* Bb = Bt + (size_t)bn * K;
    const int lrow = lane >> 2;       // 0..15 (row within 16-row chunk)
    const int lcol = (lane & 3) * 8;  // 8-element (16B) column chunk
    const int quad = lane >> 4, tm = lane & 15;

    floatx4 acc[4][4] = {};

    for (int k0 = 0; k0 < K; k0 += 32) {
#pragma unroll
        for (int i = 0; i < 2; ++i) {
            const int chunk = wave * 2 + i;     // 0..7, wave-uniform
            const int row = chunk * 16 + lrow;  // 0..127
            gl_lds16(Ab + (size_t)row * K + k0 + lcol, As + chunk * 512);
            gl_lds16(Bb + (size_t)row * K + k0 + lcol, Bs + chunk * 512);
        }
        __syncthreads();
        bf16x8 af[4], bfv[4];
#pragma unroll
        for (int mi = 0; mi < 4; ++mi)
            af[mi] = *(const bf16x8*)(As + (wm * 64 + mi * 16 + tm) * 32 + quad * 8);
#pragma unroll
        for (int ni = 0; ni < 4; ++ni)
            bfv[ni] = *(const bf16x8*)(Bs + (wn * 64 + ni * 16 + tm) * 32 + quad * 8);
#pragma unroll
        for (int mi = 0; mi < 4; ++mi)
#pragma unroll
            for (int ni = 0; ni < 4; ++ni)
                acc[mi][ni] = __builtin_amdgcn_mfma_f32_16x16x32_bf16(
                    af[mi], bfv[ni], acc[mi][ni], 0, 0, 0);
        __syncthreads();
    }

#pragma unroll
    for (int ni = 0; ni < 4; ++ni) {
        const int gc = bn + wn * 64 + ni * 16 + tm;
        const float bias = (gc < 1024) ? b0[gc]
                         : (gc < 2048) ? b1[gc - 1024]
                                       : b2[gc - 2048];
#pragma unroll
        for (int mi = 0; mi < 4; ++mi) {
            const int gr = bm + wm * 64 + mi * 16 + quad * 4;
#pragma unroll
            for (int r = 0; r < 4; ++r) {
                const float v = acc[mi][ni][r] + bias;
                if (BF16_OUT)
                    ((__bf16*)Cv)[(size_t)(gr + r) * N + gc] = (__bf16)v;
                else
                    ((float*)Cv)[(size_t)(gr + r) * N + gc] = v;
            }
        }
    }
}

// ---------------------------------------------------------------------------
// Flash-style causal attention, bf16 in/out, fp32 compute.
// QKV layout: [4096][3072] bf16, row = b*T+t; Q cols h*64.., K 1024+h*64..,
// V 2048+h*64.. Grid (T/64, B*H), block 256.
// Each thread: rows (q0+qi, q0+qi+32), 8 cols c0..c0+7. Online softmax fully
// in registers via 8-lane shuffle reductions (rows live within one wave, so
// Sm/P round-trips need no barrier). 2 barriers per K-tile.
// LDS strides chosen so all hot accesses are <=2-way (free per m136).
// ---------------------------------------------------------------------------
__global__ __launch_bounds__(256) void attn_causal(const __bf16* __restrict__ QKV,
                                                   __bf16* __restrict__ ctx) {
    constexpr float SCALE = 0.125f;  // 1/sqrt(64)
    constexpr float NEG = -1e30f;

    __shared__ float Qs[64][68];    // [q][d], stride 68: conflict-free q-indexed reads
    __shared__ float Kt[64][64];    // [d][k], stride 64: conflict-free d-row reads
    __shared__ float Vs[64][68];    // [k][d]
    __shared__ __bf16 Sm[64][72];   // probabilities (bf16, 144B rows -> aligned)

    const int tid = threadIdx.x;
    const int bh = blockIdx.y;
    const int b = bh >> 4, h = bh & 15;
    const int q0 = ((int)gridDim.x - 1 - (int)blockIdx.x) * 64;  // heavy blocks first
    const __bf16* Qb = QKV + ((size_t)b * Tc) * 3072 + h * 64;
    const __bf16* Kb = Qb + 1024;
    const __bf16* Vb = Qb + 2048;

    const int qi = tid >> 3;       // 0..31 -> rows qi, qi+32
    const int c0 = (tid & 7) * 8;  // 8-wide column slice

    // Q staging (wave-local: each wave writes exactly the rows it later reads)
    {
        const bf16x8 a = *(const bf16x8*)(Qb + (size_t)(q0 + qi) * 3072 + c0);
        const bf16x8 c = *(const bf16x8*)(Qb + (size_t)(q0 + qi + 32) * 3072 + c0);
#pragma unroll
        for (int j = 0; j < 8; ++j) {
            Qs[qi][c0 + j] = (float)a[j];
            Qs[qi + 32][c0 + j] = (float)c[j];
        }
    }

    float o0[8] = {}, o1[8] = {};
    float m0 = NEG, m1 = NEG, l0 = 0.f, l1 = 0.f;
    const int q_lo = q0 + qi, q_hi = q0 + qi + 32;
    const int kr = tid >> 2, dbase = (tid & 3) * 16;

    for (int k0 = 0; k0 <= q0; k0 += 64) {
        __syncthreads();  // prior-iter PV reads of Vs done before restage
        // --- stage K (transposed) and V tiles, bf16 global loads ---
        {
            const __bf16* kp = Kb + (size_t)(k0 + kr) * 3072 + dbase;
            const __bf16* vp = Vb + (size_t)(k0 + kr) * 3072 + dbase;
            const bf16x8 ka = *(const bf16x8*)kp, kb2 = *(const bf16x8*)(kp + 8);
            const bf16x8 va = *(const bf16x8*)vp, vb2 = *(const bf16x8*)(vp + 8);
            float kf[16], vf[16];
#pragma unroll
            for (int j = 0; j < 8; ++j) {
                kf[j] = (float)ka[j]; kf[8 + j] = (float)kb2[j];
                vf[j] = (float)va[j]; vf[8 + j] = (float)vb2[j];
            }
#pragma unroll
            for (int i = 0; i < 16; ++i) Kt[dbase + i][kr] = kf[i];
#pragma unroll
            for (int u = 0; u < 4; ++u) {
                floatx4 tv;
                tv[0] = vf[4*u]; tv[1] = vf[4*u+1]; tv[2] = vf[4*u+2]; tv[3] = vf[4*u+3];
                *(floatx4*)&Vs[kr][dbase + 4 * u] = tv;
            }
        }
        __syncthreads();

        // --- S = Q K^T (2 rows x 8 cols per thread) ---
        float s0[8] = {}, s1[8] = {};
        for (int d4 = 0; d4 < 64; d4 += 4) {
            const floatx4 qa = *(const floatx4*)&Qs[qi][d4];
            const floatx4 qc = *(const floatx4*)&Qs[qi + 32][d4];
#pragma unroll
            for (int u = 0; u < 4; ++u) {
                const floatx4 k1 = *(const floatx4*)&Kt[d4 + u][c0];
                const floatx4 k2 = *(const floatx4*)&Kt[d4 + u][c0 + 4];
#pragma unroll
                for (int j = 0; j < 4; ++j) {
                    s0[j]     += qa[u] * k1[j];
                    s0[4 + j] += qa[u] * k2[j];
                    s1[j]     += qc[u] * k1[j];
                    s1[4 + j] += qc[u] * k2[j];
                }
            }
        }
#pragma unroll
        for (int j = 0; j < 8; ++j) { s0[j] *= SCALE; s1[j] *= SCALE; }
        if (k0 == q0) {  // only the diagonal tile needs masking
#pragma unroll
            for (int j = 0; j < 8; ++j) {
                const int kk = k0 + c0 + j;
                if (kk > q_lo) s0[j] = NEG;
                if (kk > q_hi) s1[j] = NEG;
            }
        }

        // --- online softmax, fully parallel (8-lane shuffle reductions) ---
        float rm0 = s0[0], rm1 = s1[0];
#pragma unroll
        for (int j = 1; j < 8; ++j) { rm0 = fmaxf(rm0, s0[j]); rm1 = fmaxf(rm1, s1[j]); }
#pragma unroll
        for (int off = 1; off < 8; off <<= 1) {
            rm0 = fmaxf(rm0, __shfl_xor(rm0, off));
            rm1 = fmaxf(rm1, __shfl_xor(rm1, off));
        }
        const float nm0 = fmaxf(m0, rm0), nm1 = fmaxf(m1, rm1);
        float p0[8], p1[8];
        float sum0 = 0.f, sum1 = 0.f;
#pragma unroll
        for (int j = 0; j < 8; ++j) {
            p0[j] = __expf(s0[j] - nm0); sum0 += p0[j];
            p1[j] = __expf(s1[j] - nm1); sum1 += p1[j];
        }
#pragma unroll
        for (int off = 1; off < 8; off <<= 1) {
            sum0 += __shfl_xor(sum0, off);
            sum1 += __shfl_xor(sum1, off);
        }
        const float a0 = __expf(m0 - nm0), a1 = __expf(m1 - nm1);
        m0 = nm0; m1 = nm1;
        l0 = l0 * a0 + sum0; l1 = l1 * a1 + sum1;

        // --- P to LDS (bf16), same-wave write->read ---
        bf16x8 pb0, pb1;
#pragma unroll
        for (int j = 0; j < 8; ++j) { pb0[j] = (__bf16)p0[j]; pb1[j] = (__bf16)p1[j]; }
        *(bf16x8*)&Sm[qi][c0] = pb0;
        *(bf16x8*)&Sm[qi + 32][c0] = pb1;

#pragma unroll
        for (int j = 0; j < 8; ++j) { o0[j] *= a0; o1[j] *= a1; }

        // --- O += P @ V ---
        for (int k8 = 0; k8 < 64; k8 += 8) {
            const bf16x8 pa = *(const bf16x8*)&Sm[qi][k8];
            const bf16x8 pc = *(const bf16x8*)&Sm[qi + 32][k8];
#pragma unroll
            for (int u = 0; u < 8; ++u) {
                const float pka = (float)pa[u], pkc = (float)pc[u];
                const floatx4 v1 = *(const floatx4*)&Vs[k8 + u][c0];
                const floatx4 v2 = *(const floatx4*)&Vs[k8 + u][c0 + 4];
#pragma unroll
                for (int j = 0; j < 4; ++j) {
                    o0[j]     += pka * v1[j];
                    o0[4 + j] += pka * v2[j];
                    o1[j]     += pkc * v1[j];
                    o1[4 + j] += pkc * v2[j];
                }
            }
        }
    }

    const float inv0 = 1.f / l0, inv1 = 1.f / l1;
    bf16x8 r0, r1;
#pragma unroll
    for (int j = 0; j < 8; ++j) {
        r0[j] = (__bf16)(o0[j] * inv0);
        r1[j] = (__bf16)(o1[j] * inv1);
    }
    __bf16* cp = ctx + (size_t)(b * Tc + q0 + qi) * 1024 + h * 64 + c0;
    *(bf16x8*)cp = r0;
    *(bf16x8*)(cp + (size_t)32 * 1024) = r1;
}

// ---------------------------------------------------------------------------
// kernel_launch.  Workspace (bf16): xb 4M | Wqkv_t 3M | Wo_t 1M | QKVb 12M |
// ctxb 4M elements = 48 MB total.
// ---------------------------------------------------------------------------
extern "C" void kernel_launch(void* const* d_in, const int* in_sizes, int n_in,
                              void* d_out, int out_size, void* d_ws, size_t ws_size,
                              hipStream_t stream) {
    const float* x  = (const float*)d_in[0];
    const float* Wq = (const float*)d_in[1];
    const float* bq = (const float*)d_in[2];
    const float* Wk = (const float*)d_in[3];
    const float* bk = (const float*)d_in[4];
    const float* Wv = (const float*)d_in[5];
    const float* bv = (const float*)d_in[6];
    const float* Wo = (const float*)d_in[7];
    const float* bo = (const float*)d_in[8];

    __bf16* xb   = (__bf16*)d_ws;                       // [4096][1024]
    __bf16* Wqkv = xb + (size_t)Mc * 1024;              // [3072][1024] (B^T)
    __bf16* Wot  = Wqkv + (size_t)3072 * 1024;          // [1024][1024] (B^T)
    __bf16* QKVb = Wot + (size_t)1024 * 1024;           // [4096][3072]
    __bf16* ctxb = QKVb + (size_t)Mc * 3072;            // [4096][1024]

    cvt_bf16<<<4096, 256, 0, stream>>>(x, xb, Mc * 1024);
    wtrans_bf16<<<dim3(16, 16), 256, 0, stream>>>(Wq, Wqkv);
    wtrans_bf16<<<dim3(16, 16), 256, 0, stream>>>(Wk, Wqkv + (size_t)1024 * 1024);
    wtrans_bf16<<<dim3(16, 16), 256, 0, stream>>>(Wv, Wqkv + (size_t)2048 * 1024);
    wtrans_bf16<<<dim3(16, 16), 256, 0, stream>>>(Wo, Wot);

    gemm_bt<true><<<dim3(24, 32), 256, 0, stream>>>(xb, Wqkv, bq, bk, bv,
                                                    QKVb, Mc, 3072, 1024);

    attn_causal<<<dim3(32, 32), 256, 0, stream>>>(QKVb, ctxb);

    gemm_bt<false><<<dim3(8, 32), 256, 0, stream>>>(ctxb, Wot, bo, bo, bo,
                                                    d_out, Mc, 1024, 1024);
}

// Round 3
// 288.370 us; speedup vs baseline: 7.7447x; 2.5572x over previous
//
#include <hip/hip_runtime.h>
#include <hip/hip_bf16.h>

// Problem constants: B=2, T=2048, D=1024, H=16, DK=64
constexpr int Bc = 2;
constexpr int Tc = 2048;
constexpr int Mc = Bc * Tc;  // 4096

typedef __attribute__((ext_vector_type(8))) __bf16 bf16x8;
typedef __attribute__((ext_vector_type(4))) __bf16 bf16x4;
typedef __attribute__((ext_vector_type(4))) float floatx4;

__device__ __forceinline__ void gl_lds16(const void* g, void* l) {
    __builtin_amdgcn_global_load_lds(
        (const __attribute__((address_space(1))) void*)g,
        (__attribute__((address_space(3))) void*)l, 16, 0, 0);
}

// ---------------------------------------------------------------------------
// fp32 -> bf16 elementwise convert
// ---------------------------------------------------------------------------
__global__ __launch_bounds__(256) void cvt_bf16(const float* __restrict__ in,
                                                __bf16* __restrict__ out, int n) {
    const int i = (blockIdx.x * 256 + threadIdx.x) * 4;
    if (i < n) {
        const float4 v = *(const float4*)(in + i);
        bf16x4 r;
        r[0] = (__bf16)v.x; r[1] = (__bf16)v.y;
        r[2] = (__bf16)v.z; r[3] = (__bf16)v.w;
        *(bf16x4*)(out + i) = r;
    }
}

// ---------------------------------------------------------------------------
// Weight transpose+convert: W fp32 [1024][1024] (in,out) -> Wt bf16 (out,in)
// ---------------------------------------------------------------------------
__global__ __launch_bounds__(256) void wtrans_bf16(const float* __restrict__ W,
                                                   __bf16* __restrict__ Wt) {
    __shared__ float t[64][65];
    const int k0 = blockIdx.y * 64, n0 = blockIdx.x * 64;
    const int c = threadIdx.x & 63, r0 = threadIdx.x >> 6;
#pragma unroll
    for (int i = 0; i < 16; ++i)
        t[r0 + i * 4][c] = W[(size_t)(k0 + r0 + i * 4) * 1024 + n0 + c];
    __syncthreads();
#pragma unroll
    for (int i = 0; i < 16; ++i) {
        const int r = r0 + i * 4;
        Wt[(size_t)(n0 + r) * 1024 + k0 + c] = (__bf16)t[c][r];
    }
}

// ---------------------------------------------------------------------------
// bf16 MFMA GEMM (m97 structure): C[M,N] = A[M,K] @ Bt[N,K]^T + bias
// ---------------------------------------------------------------------------
template <bool BF16_OUT>
__global__ __launch_bounds__(256) void gemm_bt(const __bf16* __restrict__ A,
                                               const __bf16* __restrict__ Bt,
                                               const float* __restrict__ b0,
                                               const float* __restrict__ b1,
                                               const float* __restrict__ b2,
                                               void* __restrict__ Cv,
                                               int M, int N, int K) {
    __shared__ __bf16 As[128 * 32];
    __shared__ __bf16 Bs[128 * 32];
    const int tid = threadIdx.x, lane = tid & 63, wave = tid >> 6;
    const int wm = wave & 1, wn = wave >> 1;
    const int bm = blockIdx.y * 128, bn = blockIdx.x * 128;
    const __bf16* Ab = A + (size_t)bm * K;
    const __bf16* Bb = Bt + (size_t)bn * K;
    const int lrow = lane >> 2;
    const int lcol = (lane & 3) * 8;
    const int quad = lane >> 4, tm = lane & 15;

    floatx4 acc[4][4] = {};

    for (int k0 = 0; k0 < K; k0 += 32) {
#pragma unroll
        for (int i = 0; i < 2; ++i) {
            const int chunk = wave * 2 + i;
            const int row = chunk * 16 + lrow;
            gl_lds16(Ab + (size_t)row * K + k0 + lcol, As + chunk * 512);
            gl_lds16(Bb + (size_t)row * K + k0 + lcol, Bs + chunk * 512);
        }
        __syncthreads();
        bf16x8 af[4], bfv[4];
#pragma unroll
        for (int mi = 0; mi < 4; ++mi)
            af[mi] = *(const bf16x8*)(As + (wm * 64 + mi * 16 + tm) * 32 + quad * 8);
#pragma unroll
        for (int ni = 0; ni < 4; ++ni)
            bfv[ni] = *(const bf16x8*)(Bs + (wn * 64 + ni * 16 + tm) * 32 + quad * 8);
#pragma unroll
        for (int mi = 0; mi < 4; ++mi)
#pragma unroll
            for (int ni = 0; ni < 4; ++ni)
                acc[mi][ni] = __builtin_amdgcn_mfma_f32_16x16x32_bf16(
                    af[mi], bfv[ni], acc[mi][ni], 0, 0, 0);
        __syncthreads();
    }

#pragma unroll
    for (int ni = 0; ni < 4; ++ni) {
        const int gc = bn + wn * 64 + ni * 16 + tm;
        const float bias = (gc < 1024) ? b0[gc]
                         : (gc < 2048) ? b1[gc - 1024]
                                       : b2[gc - 2048];
#pragma unroll
        for (int mi = 0; mi < 4; ++mi) {
            const int gr = bm + wm * 64 + mi * 16 + quad * 4;
#pragma unroll
            for (int r = 0; r < 4; ++r) {
                const float v = acc[mi][ni][r] + bias;
                if (BF16_OUT)
                    ((__bf16*)Cv)[(size_t)(gr + r) * N + gc] = (__bf16)v;
                else
                    ((float*)Cv)[(size_t)(gr + r) * N + gc] = v;
            }
        }
    }
}

// ---------------------------------------------------------------------------
// V transpose: QKVb V-section [t][d] -> Vt[bh][d=64][t=2048] (k-contiguous
// rows for the PV B-operand).
// ---------------------------------------------------------------------------
__global__ __launch_bounds__(256) void vtrans(const __bf16* __restrict__ QKV,
                                              __bf16* __restrict__ Vt) {
    __shared__ __bf16 sh[64][72];
    const int tid = threadIdx.x;
    const int bh = blockIdx.y, b = bh >> 4, h = bh & 15;
    const int t0 = blockIdx.x * 64;
    const int r = tid >> 2, cc = (tid & 3) * 16;
    const __bf16* src = QKV + (size_t)(b * Tc + t0 + r) * 3072 + 2048 + h * 64 + cc;
    const bf16x8 a = *(const bf16x8*)src;
    const bf16x8 bb = *(const bf16x8*)(src + 8);
#pragma unroll
    for (int j = 0; j < 8; ++j) { sh[r][cc + j] = a[j]; sh[r][cc + 8 + j] = bb[j]; }
    __syncthreads();
    const int d = tid >> 2, tc = (tid & 3) * 16;
    bf16x8 o0, o1;
#pragma unroll
    for (int j = 0; j < 8; ++j) { o0[j] = sh[tc + j][d]; o1[j] = sh[tc + 8 + j][d]; }
    __bf16* dst = Vt + ((size_t)bh * 64 + d) * 2048 + t0 + tc;
    *(bf16x8*)dst = o0;
    *(bf16x8*)(dst + 8) = o1;
}

// ---------------------------------------------------------------------------
// MFMA flash attention (causal). Grid (T/64, B*H), 256 threads = 4 waves.
// Wave w owns q rows [q0+w*16, q0+w*16+16). K/V tiles of 64, double-buffered
// in LDS via global_load_lds w/ XOR-swizzled 16B chunks (conflict-free frag
// reads, no padding -> gl_lds compatible). Per tile:
//   S (16x64) = Q.K^T via 8 mfma_16x16x32_bf16; online softmax on C-layout
//   regs (row = quad*4+reg: in-lane + 4 shfl_xor reduce); P -> per-wave LDS
//   pad (C-layout -> A-frag transform); O += P.V^T via 8 MFMA.
// ---------------------------------------------------------------------------
__global__ __launch_bounds__(256) void attn_mfma(const __bf16* __restrict__ QKV,
                                                 const __bf16* __restrict__ Vt,
                                                 __bf16* __restrict__ ctx) {
    constexpr float SCALE = 0.125f;  // 1/sqrt(64)
    constexpr float NEG = -1e30f;

    __shared__ __bf16 Ks[2][64 * 64];
    __shared__ __bf16 Vts[2][64 * 64];
    __shared__ __bf16 Pt[4][16 * 72];  // per-wave, stride 72 (2-way-free reads)

    const int tid = threadIdx.x, lane = tid & 63, w = tid >> 6;
    const int c = lane & 15, quad = lane >> 4;
    const int bh = blockIdx.y, b = bh >> 4, h = bh & 15;
    const int q0 = ((int)gridDim.x - 1 - (int)blockIdx.x) * 64;  // heavy first

    const __bf16* Kb = QKV + (size_t)(b * Tc) * 3072 + 1024 + h * 64;
    const __bf16* Vtb = Vt + (size_t)bh * 64 * 2048;

    // Q A-frags (held in registers for the whole block)
    const __bf16* Qrow = QKV + (size_t)(b * Tc + q0 + w * 16 + c) * 3072 + h * 64;
    const bf16x8 qf0 = *(const bf16x8*)(Qrow + quad * 8);
    const bf16x8 qf1 = *(const bf16x8*)(Qrow + 32 + quad * 8);

    floatx4 oacc[4] = {};
    float m[4], l[4];
#pragma unroll
    for (int r = 0; r < 4; ++r) { m[r] = NEG; l[r] = 0.f; }

    const int nk = q0 / 64 + 1;

    // stage tile 0 into buf 0 (chunk s: row=s>>3, phys col s&7 <- logical
    // col (s&7)^(row&7); lds dst = base + s*16B = wave-uniform + lane*16B)
#pragma unroll
    for (int i = 0; i < 2; ++i) {
        const int s = i * 256 + tid;
        const int row = s >> 3;
        const int lc = (s & 7) ^ (row & 7);
        gl_lds16(Kb + (size_t)row * 3072 + lc * 8, &Ks[0][s * 8]);
        gl_lds16(Vtb + (size_t)row * 2048 + lc * 8, &Vts[0][s * 8]);
    }
    __syncthreads();

    for (int kt = 0; kt < nk; ++kt) {
        const int buf = kt & 1;
        if (kt + 1 < nk) {
            const int k0n = (kt + 1) * 64;
#pragma unroll
            for (int i = 0; i < 2; ++i) {
                const int s = i * 256 + tid;
                const int row = s >> 3;
                const int lc = (s & 7) ^ (row & 7);
                gl_lds16(Kb + (size_t)(k0n + row) * 3072 + lc * 8, &Ks[buf ^ 1][s * 8]);
                gl_lds16(Vtb + (size_t)row * 2048 + k0n + lc * 8, &Vts[buf ^ 1][s * 8]);
            }
        }
        const bool diag = (kt == nk - 1);
        const __bf16* ks = Ks[buf];
        const __bf16* vs = Vts[buf];

        // --- S = Q.K^T ---
        float sv[4][4];  // [ni][r]
#pragma unroll
        for (int ni = 0; ni < 4; ++ni) {
            if (!diag || ni <= w) {
                const int krow = ni * 16 + c;
                const int sw = krow & 7;
                const bf16x8 kb0 = *(const bf16x8*)(ks + krow * 64 + (quad ^ sw) * 8);
                const bf16x8 kb1 = *(const bf16x8*)(ks + krow * 64 + ((4 + quad) ^ sw) * 8);
                floatx4 a = {};
                a = __builtin_amdgcn_mfma_f32_16x16x32_bf16(qf0, kb0, a, 0, 0, 0);
                a = __builtin_amdgcn_mfma_f32_16x16x32_bf16(qf1, kb1, a, 0, 0, 0);
#pragma unroll
                for (int r = 0; r < 4; ++r) sv[ni][r] = a[r] * SCALE;
                if (diag && ni == w) {
#pragma unroll
                    for (int r = 0; r < 4; ++r)
                        if (c > quad * 4 + r) sv[ni][r] = NEG;
                }
            } else {
#pragma unroll
                for (int r = 0; r < 4; ++r) sv[ni][r] = NEG;
            }
        }

        // --- online softmax (rows = quad*4+r; reduce over 16-lane group) ---
        float alpha[4];
#pragma unroll
        for (int r = 0; r < 4; ++r) {
            float rm = fmaxf(fmaxf(sv[0][r], sv[1][r]), fmaxf(sv[2][r], sv[3][r]));
            rm = fmaxf(rm, __shfl_xor(rm, 1));
            rm = fmaxf(rm, __shfl_xor(rm, 2));
            rm = fmaxf(rm, __shfl_xor(rm, 4));
            rm = fmaxf(rm, __shfl_xor(rm, 8));
            const float nm = fmaxf(m[r], rm);
            alpha[r] = __expf(m[r] - nm);
            m[r] = nm;
            float rs = 0.f;
#pragma unroll
            for (int ni = 0; ni < 4; ++ni) {
                const float p = __expf(sv[ni][r] - nm);
                sv[ni][r] = p;
                rs += p;
            }
            rs += __shfl_xor(rs, 1);
            rs += __shfl_xor(rs, 2);
            rs += __shfl_xor(rs, 4);
            rs += __shfl_xor(rs, 8);
            l[r] = l[r] * alpha[r] + rs;
        }

        // --- P: C-layout regs -> per-wave LDS -> A-frags ---
#pragma unroll
        for (int ni = 0; ni < 4; ++ni)
#pragma unroll
            for (int r = 0; r < 4; ++r)
                Pt[w][(quad * 4 + r) * 72 + ni * 16 + c] = (__bf16)sv[ni][r];
        __asm__ volatile("s_waitcnt lgkmcnt(0)" ::: "memory");
        const bf16x8 pa0 = *(const bf16x8*)&Pt[w][c * 72 + quad * 8];
        const bf16x8 pa1 = *(const bf16x8*)&Pt[w][c * 72 + 32 + quad * 8];

        // --- rescale O, O += P.V^T ---
#pragma unroll
        for (int di = 0; di < 4; ++di)
#pragma unroll
            for (int r = 0; r < 4; ++r) oacc[di][r] *= alpha[r];
#pragma unroll
        for (int di = 0; di < 4; ++di) {
            const int drow = di * 16 + c;
            const int sw = drow & 7;
            const bf16x8 vb0 = *(const bf16x8*)(vs + drow * 64 + (quad ^ sw) * 8);
            const bf16x8 vb1 = *(const bf16x8*)(vs + drow * 64 + ((4 + quad) ^ sw) * 8);
            oacc[di] = __builtin_amdgcn_mfma_f32_16x16x32_bf16(pa0, vb0, oacc[di], 0, 0, 0);
            oacc[di] = __builtin_amdgcn_mfma_f32_16x16x32_bf16(pa1, vb1, oacc[di], 0, 0, 0);
        }
        __syncthreads();  // all waves done with buf; next stage completed
    }

    // --- epilogue: O C-layout (row=quad*4+r local q, col=di*16+c local d) ---
    float inv[4];
#pragma unroll
    for (int r = 0; r < 4; ++r) inv[r] = 1.f / l[r];
    __bf16* cp = ctx + (size_t)(b * Tc + q0 + w * 16 + quad * 4) * 1024 + h * 64 + c;
#pragma unroll
    for (int r = 0; r < 4; ++r)
#pragma unroll
        for (int di = 0; di < 4; ++di)
            cp[(size_t)r * 1024 + di * 16] = (__bf16)(oacc[di][r] * inv[r]);
}

// ---------------------------------------------------------------------------
// kernel_launch.  Workspace (bf16 elements): xb 4M | Wqkv 3M | Wot 1M |
// QKVb 12M | ctxb 4M | Vt 4M  = 28M elements = 56 MB.
// ---------------------------------------------------------------------------
extern "C" void kernel_launch(void* const* d_in, const int* in_sizes, int n_in,
                              void* d_out, int out_size, void* d_ws, size_t ws_size,
                              hipStream_t stream) {
    const float* x  = (const float*)d_in[0];
    const float* Wq = (const float*)d_in[1];
    const float* bq = (const float*)d_in[2];
    const float* Wk = (const float*)d_in[3];
    const float* bk = (const float*)d_in[4];
    const float* Wv = (const float*)d_in[5];
    const float* bv = (const float*)d_in[6];
    const float* Wo = (const float*)d_in[7];
    const float* bo = (const float*)d_in[8];

    __bf16* xb   = (__bf16*)d_ws;                       // [4096][1024]
    __bf16* Wqkv = xb + (size_t)Mc * 1024;              // [3072][1024] (B^T)
    __bf16* Wot  = Wqkv + (size_t)3072 * 1024;          // [1024][1024] (B^T)
    __bf16* QKVb = Wot + (size_t)1024 * 1024;           // [4096][3072]
    __bf16* ctxb = QKVb + (size_t)Mc * 3072;            // [4096][1024]
    __bf16* Vtw  = ctxb + (size_t)Mc * 1024;            // [32][64][2048]

    cvt_bf16<<<4096, 256, 0, stream>>>(x, xb, Mc * 1024);
    wtrans_bf16<<<dim3(16, 16), 256, 0, stream>>>(Wq, Wqkv);
    wtrans_bf16<<<dim3(16, 16), 256, 0, stream>>>(Wk, Wqkv + (size_t)1024 * 1024);
    wtrans_bf16<<<dim3(16, 16), 256, 0, stream>>>(Wv, Wqkv + (size_t)2048 * 1024);
    wtrans_bf16<<<dim3(16, 16), 256, 0, stream>>>(Wo, Wot);

    gemm_bt<true><<<dim3(24, 32), 256, 0, stream>>>(xb, Wqkv, bq, bk, bv,
                                                    QKVb, Mc, 3072, 1024);

    vtrans<<<dim3(32, 32), 256, 0, stream>>>(QKVb, Vtw);

    attn_mfma<<<dim3(32, 32), 256, 0, stream>>>(QKVb, Vtw, ctxb);

    gemm_bt<false><<<dim3(8, 32), 256, 0, stream>>>(ctxb, Wot, bo, bo, bo,
                                                    d_out, Mc, 1024, 1024);
}

// Round 4
// 209.573 us; speedup vs baseline: 10.6566x; 1.3760x over previous
//
#include <hip/hip_runtime.h>
#include <hip/hip_bf16.h>

// Problem constants: B=2, T=2048, D=1024, H=16, DK=64
constexpr int Bc = 2;
constexpr int Tc = 2048;
constexpr int Mc = Bc * Tc;  // 4096

typedef __attribute__((ext_vector_type(8))) __bf16 bf16x8;
typedef __attribute__((ext_vector_type(4))) __bf16 bf16x4;
typedef __attribute__((ext_vector_type(4))) float floatx4;

__device__ __forceinline__ void gl_lds16(const void* g, void* l) {
    __builtin_amdgcn_global_load_lds(
        (const __attribute__((address_space(1))) void*)g,
        (__attribute__((address_space(3))) void*)l, 16, 0, 0);
}

// ---------------------------------------------------------------------------
// fp32 -> bf16 elementwise convert
// ---------------------------------------------------------------------------
__global__ __launch_bounds__(256) void cvt_bf16(const float* __restrict__ in,
                                                __bf16* __restrict__ out, int n) {
    const int i = (blockIdx.x * 256 + threadIdx.x) * 4;
    if (i < n) {
        const float4 v = *(const float4*)(in + i);
        bf16x4 r;
        r[0] = (__bf16)v.x; r[1] = (__bf16)v.y;
        r[2] = (__bf16)v.z; r[3] = (__bf16)v.w;
        *(bf16x4*)(out + i) = r;
    }
}

// ---------------------------------------------------------------------------
// All 4 weight transposes in one launch. z: 0..2 -> Wq/Wk/Wv into Wqkv
// sections; 3 -> Wo into Wot. W fp32 (in,out) -> Wt bf16 (out,in).
// ---------------------------------------------------------------------------
__global__ __launch_bounds__(256) void wtrans_all(const float* __restrict__ Wq,
                                                  const float* __restrict__ Wk,
                                                  const float* __restrict__ Wv,
                                                  const float* __restrict__ Wo,
                                                  __bf16* __restrict__ Wqkv,
                                                  __bf16* __restrict__ Wot) {
    __shared__ float t[64][65];
    const int z = blockIdx.z;
    const float* W = (z == 0) ? Wq : (z == 1) ? Wk : (z == 2) ? Wv : Wo;
    __bf16* Wt = (z < 3) ? Wqkv + (size_t)z * 1024 * 1024 : Wot;
    const int k0 = blockIdx.y * 64, n0 = blockIdx.x * 64;
    const int c = threadIdx.x & 63, r0 = threadIdx.x >> 6;
#pragma unroll
    for (int i = 0; i < 16; ++i)
        t[r0 + i * 4][c] = W[(size_t)(k0 + r0 + i * 4) * 1024 + n0 + c];
    __syncthreads();
#pragma unroll
    for (int i = 0; i < 16; ++i) {
        const int r = r0 + i * 4;
        Wt[(size_t)(n0 + r) * 1024 + k0 + c] = (__bf16)t[c][r];
    }
}

// ---------------------------------------------------------------------------
// bf16 MFMA GEMM: C[M,TNgrid] = A[M,K] @ Bt[N,K]^T + bias.
// 128xTN tile (TN=128 or 64), 256 threads = 4 waves.
// FUSE_VT: columns >=2048 (the V projection) are written transposed into
// Vt[bh][d][t] instead of C — fuses the attention V-transpose for free.
// ---------------------------------------------------------------------------
template <int TN, bool BF16_OUT, bool FUSE_VT>
__global__ __launch_bounds__(256) void gemm_bt(const __bf16* __restrict__ A,
                                               const __bf16* __restrict__ Bt,
                                               const float* __restrict__ b0,
                                               const float* __restrict__ b1,
                                               const float* __restrict__ b2,
                                               void* __restrict__ Cv,
                                               __bf16* __restrict__ Vt,
                                               int K, int ldc) {
    constexpr int NI = TN / 32;  // accs per wave in n (4 or 2)
    __shared__ __bf16 As[128 * 32];
    __shared__ __bf16 Bs[TN * 32];
    const int tid = threadIdx.x, lane = tid & 63, wave = tid >> 6;
    const int wm = wave & 1, wn = wave >> 1;
    const int bm = blockIdx.y * 128, bn = blockIdx.x * TN;
    const __bf16* Ab = A + (size_t)bm * K;
    const __bf16* Bb = Bt + (size_t)bn * K;
    const int quad = lane >> 4, tm = lane & 15;

    floatx4 acc[4][NI] = {};

    for (int k0 = 0; k0 < K; k0 += 32) {
#pragma unroll
        for (int i = 0; i < 2; ++i) {
            const int s = i * 256 + tid;
            gl_lds16(Ab + (size_t)(s >> 2) * K + k0 + (s & 3) * 8, As + s * 8);
        }
        if (TN == 128) {
#pragma unroll
            for (int i = 0; i < 2; ++i) {
                const int s = i * 256 + tid;
                gl_lds16(Bb + (size_t)(s >> 2) * K + k0 + (s & 3) * 8, Bs + s * 8);
            }
        } else {
            const int s = tid;
            gl_lds16(Bb + (size_t)(s >> 2) * K + k0 + (s & 3) * 8, Bs + s * 8);
        }
        __syncthreads();
        bf16x8 af[4], bfv[NI];
#pragma unroll
        for (int mi = 0; mi < 4; ++mi)
            af[mi] = *(const bf16x8*)(As + (wm * 64 + mi * 16 + tm) * 32 + quad * 8);
#pragma unroll
        for (int ni = 0; ni < NI; ++ni)
            bfv[ni] = *(const bf16x8*)(Bs + (wn * (TN / 2) + ni * 16 + tm) * 32 + quad * 8);
#pragma unroll
        for (int mi = 0; mi < 4; ++mi)
#pragma unroll
            for (int ni = 0; ni < NI; ++ni)
                acc[mi][ni] = __builtin_amdgcn_mfma_f32_16x16x32_bf16(
                    af[mi], bfv[ni], acc[mi][ni], 0, 0, 0);
        __syncthreads();
    }

#pragma unroll
    for (int ni = 0; ni < NI; ++ni) {
        const int gc = bn + wn * (TN / 2) + ni * 16 + tm;
        const float bias = (gc < 1024) ? b0[gc]
                         : (gc < 2048) ? b1[gc - 1024]
                                       : b2[gc - 2048];
#pragma unroll
        for (int mi = 0; mi < 4; ++mi) {
            const int gr0 = bm + wm * 64 + mi * 16 + quad * 4;
            if (FUSE_VT && gc >= 2048) {
                bf16x4 pv;
#pragma unroll
                for (int r = 0; r < 4; ++r) pv[r] = (__bf16)(acc[mi][ni][r] + bias);
                const int bb = gr0 >> 11, tloc = gr0 & 2047;
                const int hh = (gc - 2048) >> 6, dd = gc & 63;
                *(bf16x4*)(Vt + ((size_t)(bb * 16 + hh) * 64 + dd) * 2048 + tloc) = pv;
            } else if (BF16_OUT) {
#pragma unroll
                for (int r = 0; r < 4; ++r)
                    ((__bf16*)Cv)[(size_t)(gr0 + r) * ldc + gc] =
                        (__bf16)(acc[mi][ni][r] + bias);
            } else {
#pragma unroll
                for (int r = 0; r < 4; ++r)
                    ((float*)Cv)[(size_t)(gr0 + r) * ldc + gc] =
                        acc[mi][ni][r] + bias;
            }
        }
    }
}

// ---------------------------------------------------------------------------
// MFMA flash attention (causal), S^T formulation + triangle pairing.
// Grid (16, B*H), 256 threads = 4 waves. Block bx handles q-tiles bx (A) and
// 31-bx (B) -> exactly 33 tile-computes per block (perfect balance).
// Wave w owns q rows w*16..w*16+15 of each q-tile.
// S^T = K.Q^T: C-layout gives lane c = q-row, regs = k -> softmax is in-lane
// + 2 shuffles, and P feeds PV straight from registers (slot-permuted
// O^T = V^T.P^T, only 16x16x32 MFMA). K/V tiles (64) double-buffered via
// swizzled global_load_lds; staging + V-frags shared by both q-groups.
// ---------------------------------------------------------------------------
__global__ __launch_bounds__(256) void attn_mfma(const __bf16* __restrict__ QK,
                                                 const __bf16* __restrict__ Vt,
                                                 __bf16* __restrict__ ctx) {
    constexpr float Cf = 0.18033688011112042f;  // (1/sqrt(64)) * log2(e)
    constexpr float NEG = -1e30f;

    __shared__ __bf16 Ks[2][64 * 64];
    __shared__ __bf16 Vts[2][64 * 64];

    const int tid = threadIdx.x, lane = tid & 63, w = tid >> 6;
    const int c = lane & 15, quad = lane >> 4;
    const int bh = blockIdx.y, b = bh >> 4, h = bh & 15;
    const int ta = blockIdx.x, tb = 31 - ta;
    const int tg[2] = {tb, ta};  // group 0 (always active) = heavy tile
    const int nk = tb + 1;

    const __bf16* Qb = QK + (size_t)(b * Tc) * 2048 + h * 64;
    const __bf16* Kb = Qb + 1024;
    const __bf16* Vtb = Vt + (size_t)bh * 64 * 2048;

    // Q fragments (B-operand: n = q-row = lane&15), held for the whole block
    bf16x8 qf0[2], qf1[2];
#pragma unroll
    for (int g = 0; g < 2; ++g) {
        const __bf16* qr = Qb + (size_t)(tg[g] * 64 + w * 16 + c) * 2048;
        qf0[g] = *(const bf16x8*)(qr + quad * 8);
        qf1[g] = *(const bf16x8*)(qr + 32 + quad * 8);
    }

    float m[2] = {NEG, NEG}, l[2] = {0.f, 0.f};
    floatx4 oa[2][4] = {};

    // stage tile 0 (swizzled: phys chunk s holds logical col (s&7)^(row&7))
#pragma unroll
    for (int i = 0; i < 2; ++i) {
        const int s = i * 256 + tid;
        const int row = s >> 3;
        const int lc = (s & 7) ^ (row & 7);
        gl_lds16(Kb + (size_t)row * 2048 + lc * 8, &Ks[0][s * 8]);
        gl_lds16(Vtb + (size_t)row * 2048 + lc * 8, &Vts[0][s * 8]);
    }
    __syncthreads();

    for (int kt = 0; kt < nk; ++kt) {
        const int buf = kt & 1;
        if (kt + 1 < nk) {
            const int k0n = (kt + 1) * 64;
#pragma unroll
            for (int i = 0; i < 2; ++i) {
                const int s = i * 256 + tid;
                const int row = s >> 3;
                const int lc = (s & 7) ^ (row & 7);
                gl_lds16(Kb + (size_t)(k0n + row) * 2048 + lc * 8, &Ks[buf ^ 1][s * 8]);
                gl_lds16(Vtb + (size_t)row * 2048 + k0n + lc * 8, &Vts[buf ^ 1][s * 8]);
            }
        }
        const __bf16* ks = Ks[buf];
        const __bf16* vs = Vts[buf];
        const bool actA = (kt <= ta);

        // --- S^T = K.Q^T : sv[g][ni][r] = S[k=16ni+quad*4+r][q=c] ---
        float sv[2][4][4];
#pragma unroll
        for (int ni = 0; ni < 4; ++ni) {
            const int krow = ni * 16 + c;
            const int sw = krow & 7;
            const bf16x8 kb0 = *(const bf16x8*)(ks + krow * 64 + (quad ^ sw) * 8);
            const bf16x8 kb1 = *(const bf16x8*)(ks + krow * 64 + ((4 + quad) ^ sw) * 8);
            {
                floatx4 a = {};
                a = __builtin_amdgcn_mfma_f32_16x16x32_bf16(kb0, qf0[0], a, 0, 0, 0);
                a = __builtin_amdgcn_mfma_f32_16x16x32_bf16(kb1, qf1[0], a, 0, 0, 0);
#pragma unroll
                for (int r = 0; r < 4; ++r) sv[0][ni][r] = a[r];
            }
            if (actA) {
                floatx4 a = {};
                a = __builtin_amdgcn_mfma_f32_16x16x32_bf16(kb0, qf0[1], a, 0, 0, 0);
                a = __builtin_amdgcn_mfma_f32_16x16x32_bf16(kb1, qf1[1], a, 0, 0, 0);
#pragma unroll
                for (int r = 0; r < 4; ++r) sv[1][ni][r] = a[r];
            }
        }

        // --- softmax per group (raw scores; SCALE*log2e folded into exp2) ---
        bf16x8 pb[2][2];
        float alpha[2];
#pragma unroll
        for (int g = 0; g < 2; ++g) {
            if (g == 1 && !actA) continue;
            if (kt == tg[g]) {  // diagonal: mask k_loc > q_loc
#pragma unroll
                for (int ni = 0; ni < 4; ++ni)
#pragma unroll
                    for (int r = 0; r < 4; ++r)
                        if (ni * 16 + quad * 4 + r > w * 16 + c) sv[g][ni][r] = NEG;
            }
            float rm = sv[g][0][0];
#pragma unroll
            for (int ni = 0; ni < 4; ++ni)
#pragma unroll
                for (int r = 0; r < 4; ++r) rm = fmaxf(rm, sv[g][ni][r]);
            rm = fmaxf(rm, __shfl_xor(rm, 16));
            rm = fmaxf(rm, __shfl_xor(rm, 32));
            const float nm = fmaxf(m[g], rm);
            alpha[g] = __builtin_exp2f((m[g] - nm) * Cf);
            const float nmc = -nm * Cf;
            float sum = 0.f;
#pragma unroll
            for (int ni = 0; ni < 4; ++ni)
#pragma unroll
                for (int r = 0; r < 4; ++r) {
                    const float p = __builtin_exp2f(fmaf(sv[g][ni][r], Cf, nmc));
                    sv[g][ni][r] = p;
                    sum += p;
                }
            sum += __shfl_xor(sum, 16);
            sum += __shfl_xor(sum, 32);
            m[g] = nm;
            l[g] = l[g] * alpha[g] + sum;
#pragma unroll
            for (int pr = 0; pr < 2; ++pr)
#pragma unroll
                for (int j = 0; j < 4; ++j) {
                    pb[g][pr][j] = (__bf16)sv[g][pr * 2][j];
                    pb[g][pr][4 + j] = (__bf16)sv[g][pr * 2 + 1][j];
                }
#pragma unroll
            for (int di = 0; di < 4; ++di)
#pragma unroll
                for (int r = 0; r < 4; ++r) oa[g][di][r] *= alpha[g];
        }

        // --- O^T += V^T.P^T  (slot-permuted k: slot quad*8+j <-> t=16n+quad*4+j)
#pragma unroll
        for (int di = 0; di < 4; ++di) {
            const int vrow = di * 16 + c;
            const int sw2 = vrow & 7;
#pragma unroll
            for (int pr = 0; pr < 2; ++pr) {
                const int lc0 = (2 * (pr * 2) + (quad >> 1)) ^ sw2;
                const int lc1 = (2 * (pr * 2 + 1) + (quad >> 1)) ^ sw2;
                const bf16x4 va =
                    *(const bf16x4*)(vs + vrow * 64 + lc0 * 8 + (quad & 1) * 4);
                const bf16x4 vb =
                    *(const bf16x4*)(vs + vrow * 64 + lc1 * 8 + (quad & 1) * 4);
                bf16x8 vf;
#pragma unroll
                for (int j = 0; j < 4; ++j) { vf[j] = va[j]; vf[4 + j] = vb[j]; }
                oa[0][di] = __builtin_amdgcn_mfma_f32_16x16x32_bf16(
                    vf, pb[0][pr], oa[0][di], 0, 0, 0);
                if (actA)
                    oa[1][di] = __builtin_amdgcn_mfma_f32_16x16x32_bf16(
                        vf, pb[1][pr], oa[1][di], 0, 0, 0);
            }
        }
        __syncthreads();
    }

    // --- epilogue: lane holds O^T[d=di*16+quad*4+r][q=c] per group ---
#pragma unroll
    for (int g = 0; g < 2; ++g) {
        const float inv = 1.f / l[g];
        __bf16* cp = ctx + (size_t)(b * Tc + tg[g] * 64 + w * 16 + c) * 1024 +
                     h * 64 + quad * 4;
#pragma unroll
        for (int di = 0; di < 4; ++di) {
            bf16x4 rv;
#pragma unroll
            for (int r = 0; r < 4; ++r) rv[r] = (__bf16)(oa[g][di][r] * inv);
            *(bf16x4*)(cp + di * 16) = rv;
        }
    }
}

// ---------------------------------------------------------------------------
// kernel_launch. Workspace (bf16 el): xb 4M | Wqkv 3M | Wot 1M | QKb 8M |
// Vt 4M | ctxb 4M = 24M el = 48 MB.
// ---------------------------------------------------------------------------
extern "C" void kernel_launch(void* const* d_in, const int* in_sizes, int n_in,
                              void* d_out, int out_size, void* d_ws, size_t ws_size,
                              hipStream_t stream) {
    const float* x  = (const float*)d_in[0];
    const float* Wq = (const float*)d_in[1];
    const float* bq = (const float*)d_in[2];
    const float* Wk = (const float*)d_in[3];
    const float* bk = (const float*)d_in[4];
    const float* Wv = (const float*)d_in[5];
    const float* bv = (const float*)d_in[6];
    const float* Wo = (const float*)d_in[7];
    const float* bo = (const float*)d_in[8];

    __bf16* xb   = (__bf16*)d_ws;                    // [4096][1024]
    __bf16* Wqkv = xb + (size_t)Mc * 1024;           // [3072][1024] (B^T)
    __bf16* Wot  = Wqkv + (size_t)3072 * 1024;       // [1024][1024] (B^T)
    __bf16* QKb  = Wot + (size_t)1024 * 1024;        // [4096][2048]  Q|K
    __bf16* Vtw  = QKb + (size_t)Mc * 2048;          // [32][64][2048]
    __bf16* ctxb = Vtw + (size_t)32 * 64 * 2048;     // [4096][1024]

    cvt_bf16<<<4096, 256, 0, stream>>>(x, xb, Mc * 1024);
    wtrans_all<<<dim3(16, 16, 4), 256, 0, stream>>>(Wq, Wk, Wv, Wo, Wqkv, Wot);

    // QKV projection: N=3072; V columns stream transposed into Vtw
    gemm_bt<128, true, true><<<dim3(24, 32), 256, 0, stream>>>(
        xb, Wqkv, bq, bk, bv, QKb, Vtw, 1024, 2048);

    attn_mfma<<<dim3(16, 32), 256, 0, stream>>>(QKb, Vtw, ctxb);

    // Output projection: N=1024, fp32 out, 128x64 tiles for occupancy
    gemm_bt<64, false, false><<<dim3(16, 32), 256, 0, stream>>>(
        ctxb, Wot, bo, bo, bo, d_out, nullptr, 1024, 1024);
}